// Round 8
// baseline (685.438 us; speedup 1.0000x reference)
//
#include <hip/hip_runtime.h>
#include <cstdint>
#include <cstddef>

#define IN_DIM  256
#define H_DIM   256
#define OUT_DIM 128
#define MEDGES  20000

// Replicated padded adjacency: per-(segment,replica) counters cut same-line
// atomic contention (edge side: 800 -> 100 RMW/line at the coherence point).
#define REP_E 8
#define SUB_E 32          // P(Pois(50/8) >= 32) ~ 1e-10
#define CAP_E (REP_E * SUB_E)   // 256 slots, 1 KB row
#define REP_V 4
#define SUB_V 16          // P(Pois(10/4) >= 16) ~ 9e-8
#define CAP_V (REP_V * SUB_V)   // 64 slots, 256 B row

typedef unsigned short u16;
typedef unsigned int   u32;
typedef short bf16x8 __attribute__((ext_vector_type(8)));
typedef float f32x4  __attribute__((ext_vector_type(4)));

__device__ __forceinline__ float bf2f(u16 u) {
    u32 x = ((u32)u) << 16;
    float f;
    __builtin_memcpy(&f, &x, 4);
    return f;
}
// round-to-nearest-even float -> bf16 (finite inputs)
__device__ __forceinline__ u16 f2bf(float f) {
    u32 x;
    __builtin_memcpy(&x, &f, 4);
    u32 r = x + 0x7fffu + ((x >> 16) & 1u);
    return (u16)(r >> 16);
}

// ======================= fused convert fp32 -> bf16 (X, W1, W2) =======================
__global__ void cvt_all(const float4* __restrict__ X,  ushort4* __restrict__ Xb,  int nX,
                        const float4* __restrict__ W1, ushort4* __restrict__ W1b, int nW1,
                        const float4* __restrict__ W2, ushort4* __restrict__ W2b, int nW2)
{
    int i = blockIdx.x * blockDim.x + threadIdx.x;
    const float4* s; ushort4* d; int k;
    if (i < nX)                  { s = X;  d = Xb;  k = i; }
    else if (i < nX + nW1)       { s = W1; d = W1b; k = i - nX; }
    else if (i < nX + nW1 + nW2) { s = W2; d = W2b; k = i - nX - nW1; }
    else return;
    float4 v = s[k];
    ushort4 o;
    o.x = f2bf(v.x); o.y = f2bf(v.y); o.z = f2bf(v.z); o.w = f2bf(v.w);
    d[k] = o;
}

// ======================= one-pass replicated padded adjacency build =======================
__global__ void build_lists(const int* __restrict__ e_idx, const int* __restrict__ v_idx,
                            int* __restrict__ cntR_e, int* __restrict__ cntR_v,
                            int* __restrict__ e_lst, int* __restrict__ v_lst,
                            int Mpad, int Npad, int nnz)
{
    int i = blockIdx.x * blockDim.x + threadIdx.x;
    if (i >= nnz) return;
    int re = blockIdx.x & (REP_E - 1);
    int rv = blockIdx.x & (REP_V - 1);
    int e = e_idx[i], v = v_idx[i];
    int pe = atomicAdd(&cntR_e[re * Mpad + e], 1);
    if (pe < SUB_E) e_lst[(size_t)e * CAP_E + re * SUB_E + pe] = v;
    int pv = atomicAdd(&cntR_v[rv * Npad + v], 1);
    if (pv < SUB_V) v_lst[(size_t)v * CAP_V + rv * SUB_V + pv] = e;
}

// ======================= segment mean: wave-per-segment, replicated padded lists ==========
// Divisor = uncapped total across replicas (matches reference segment count).
template <int REPS, int SUB>
__global__ void seg_mean_w4(const ushort4* __restrict__ src, ushort4* __restrict__ dst,
                            const int* __restrict__ cntR, int cstride,
                            const int* __restrict__ lst, int nseg, int do_relu)
{
    int wid  = (blockIdx.x * blockDim.x + threadIdx.x) >> 6;
    int lane = threadIdx.x & 63;
    if (wid >= nseg) return;
    int nr[REPS];
    int total = 0;
#pragma unroll
    for (int r = 0; r < REPS; ++r) {
        int c = __builtin_amdgcn_readfirstlane(cntR[r * cstride + wid]);
        total += c;
        nr[r] = min(c, SUB);
    }
    const int* row = lst + (size_t)wid * (REPS * SUB);
    float ax = 0.f, ay = 0.f, az = 0.f, aw = 0.f;
#pragma unroll
    for (int r = 0; r < REPS; ++r) {
        const int* l = row + r * SUB;
        int n = nr[r];
        int j = 0;
        for (; j + 3 < n; j += 4) {
            int i0 = l[j], i1 = l[j + 1], i2 = l[j + 2], i3 = l[j + 3];
            ushort4 a = src[(size_t)i0 * 64 + lane];
            ushort4 b = src[(size_t)i1 * 64 + lane];
            ushort4 c = src[(size_t)i2 * 64 + lane];
            ushort4 d = src[(size_t)i3 * 64 + lane];
            ax += bf2f(a.x) + bf2f(b.x) + bf2f(c.x) + bf2f(d.x);
            ay += bf2f(a.y) + bf2f(b.y) + bf2f(c.y) + bf2f(d.y);
            az += bf2f(a.z) + bf2f(b.z) + bf2f(c.z) + bf2f(d.z);
            aw += bf2f(a.w) + bf2f(b.w) + bf2f(c.w) + bf2f(d.w);
        }
        for (; j < n; ++j) {
            ushort4 a = src[(size_t)l[j] * 64 + lane];
            ax += bf2f(a.x); ay += bf2f(a.y); az += bf2f(a.z); aw += bf2f(a.w);
        }
    }
    float inv = (total > 0) ? 1.f / (float)total : 0.f;
    ax *= inv; ay *= inv; az *= inv; aw *= inv;
    if (do_relu) {
        ax = fmaxf(ax, 0.f); ay = fmaxf(ay, 0.f);
        az = fmaxf(az, 0.f); aw = fmaxf(aw, 0.f);
    }
    ushort4 o;
    o.x = f2bf(ax); o.y = f2bf(ay); o.z = f2bf(az); o.w = f2bf(aw);
    dst[(size_t)wid * 64 + lane] = o;
}

template <int REPS, int SUB>
__global__ void seg_mean_w2(const ushort2* __restrict__ src, ushort2* __restrict__ dst,
                            const int* __restrict__ cntR, int cstride,
                            const int* __restrict__ lst, int nseg, int do_relu)
{
    int wid  = (blockIdx.x * blockDim.x + threadIdx.x) >> 6;
    int lane = threadIdx.x & 63;
    if (wid >= nseg) return;
    int nr[REPS];
    int total = 0;
#pragma unroll
    for (int r = 0; r < REPS; ++r) {
        int c = __builtin_amdgcn_readfirstlane(cntR[r * cstride + wid]);
        total += c;
        nr[r] = min(c, SUB);
    }
    const int* row = lst + (size_t)wid * (REPS * SUB);
    float ax = 0.f, ay = 0.f;
#pragma unroll
    for (int r = 0; r < REPS; ++r) {
        const int* l = row + r * SUB;
        int n = nr[r];
        int j = 0;
        for (; j + 3 < n; j += 4) {
            int i0 = l[j], i1 = l[j + 1], i2 = l[j + 2], i3 = l[j + 3];
            ushort2 a = src[(size_t)i0 * 64 + lane];
            ushort2 b = src[(size_t)i1 * 64 + lane];
            ushort2 c = src[(size_t)i2 * 64 + lane];
            ushort2 d = src[(size_t)i3 * 64 + lane];
            ax += bf2f(a.x) + bf2f(b.x) + bf2f(c.x) + bf2f(d.x);
            ay += bf2f(a.y) + bf2f(b.y) + bf2f(c.y) + bf2f(d.y);
        }
        for (; j < n; ++j) {
            ushort2 a = src[(size_t)l[j] * 64 + lane];
            ax += bf2f(a.x); ay += bf2f(a.y);
        }
    }
    float inv = (total > 0) ? 1.f / (float)total : 0.f;
    ax *= inv; ay *= inv;
    if (do_relu) { ax = fmaxf(ax, 0.f); ay = fmaxf(ay, 0.f); }
    ushort2 o;
    o.x = f2bf(ax); o.y = f2bf(ay);
    dst[(size_t)wid * 64 + lane] = o;
}

// ======================= MFMA bf16 GEMM + bias, bf16 out =======================
#define GSTRIDE 40   // LDS row stride in elements (80 B)
__global__ __launch_bounds__(256) void gemm_mfma_bf16(const u16* __restrict__ A,
                                                      const u16* __restrict__ W,
                                                      const float* __restrict__ bias,
                                                      u16* __restrict__ C,
                                                      int R, int K, int Cc)
{
    __shared__ __align__(16) u16 As[64 * GSTRIDE];   // [row][k] 64x32
    __shared__ __align__(16) u16 Bs[64 * GSTRIDE];   // [n][k]   64x32 (transposed)

    int tid  = threadIdx.x;
    int wave = tid >> 6;
    int lane = tid & 63;
    int quad = lane >> 4;
    int l16  = lane & 15;

    int row0 = blockIdx.y * 64;
    int col0 = blockIdx.x * 64;

    f32x4 acc[4] = {};

    int ar   = tid >> 2;   // 0..63 A row
    int aseg = tid & 3;    // k-offset 8*aseg
    int bk   = tid >> 3;   // 0..31 W k-row
    int bn   = tid & 7;    // n-offset 8*bn

    for (int k0 = 0; k0 < K; k0 += 32) {
        bf16x8 av = {};
        int gr = row0 + ar;
        if (gr < R) av = *(const bf16x8*)&A[(size_t)gr * K + k0 + 8 * aseg];
        *(bf16x8*)&As[ar * GSTRIDE + 8 * aseg] = av;
        bf16x8 wv = *(const bf16x8*)&W[(size_t)(k0 + bk) * Cc + col0 + 8 * bn];
#pragma unroll
        for (int j = 0; j < 8; ++j)
            Bs[(8 * bn + j) * GSTRIDE + bk] = ((const u16*)&wv)[j];
        __syncthreads();

        bf16x8 af = *(const bf16x8*)&As[(16 * wave + l16) * GSTRIDE + 8 * quad];
#pragma unroll
        for (int nt = 0; nt < 4; ++nt) {
            bf16x8 bfv = *(const bf16x8*)&Bs[(16 * nt + l16) * GSTRIDE + 8 * quad];
            acc[nt] = __builtin_amdgcn_mfma_f32_16x16x32_bf16(af, bfv, acc[nt], 0, 0, 0);
        }
        __syncthreads();
    }

#pragma unroll
    for (int nt = 0; nt < 4; ++nt) {
        int col = col0 + 16 * nt + l16;
        float bv = bias[col];
#pragma unroll
        for (int r = 0; r < 4; ++r) {
            int grow = row0 + 16 * wave + 4 * quad + r;
            if (grow < R) C[(size_t)grow * Cc + col] = f2bf(acc[nt][r] + bv);
        }
    }
}

// ======================= link head =======================
__global__ void link_head(const ushort2* __restrict__ h2, const int* __restrict__ link,
                          const float* __restrict__ fc_w, const float* __restrict__ fc_b,
                          float* __restrict__ out, int L)
{
    int gtid = blockIdx.x * blockDim.x + threadIdx.x;
    int wid  = gtid >> 6;
    int lane = threadIdx.x & 63;
    if (wid >= L) return;
    const int Dh = OUT_DIM / 2;   // 64 pairs
    int a = link[2 * wid + 0];
    int b = link[2 * wid + 1];
    ushort2 ra = h2[(size_t)a * Dh + lane];
    ushort2 rb = h2[(size_t)b * Dh + lane];
    float2 w = *(const float2*)&fc_w[2 * lane];
    float acc = 0.5f * ((bf2f(ra.x) + bf2f(rb.x)) * w.x + (bf2f(ra.y) + bf2f(rb.y)) * w.y);
#pragma unroll
    for (int off = 32; off; off >>= 1) acc += __shfl_xor(acc, off, 64);
    if (lane == 0) out[wid] = 1.f / (1.f + expf(-(acc + fc_b[0])));
}

// ======================= launch =======================

static inline size_t align_up(size_t x, size_t a) { return (x + a - 1) & ~(a - 1); }

extern "C" void kernel_launch(void* const* d_in, const int* in_sizes, int n_in,
                              void* d_out, int out_size, void* d_ws, size_t ws_size,
                              hipStream_t stream)
{
    const float* X   = (const float*)d_in[0];
    const float* W1  = (const float*)d_in[1];
    const float* b1  = (const float*)d_in[2];
    const float* W2  = (const float*)d_in[3];
    const float* b2  = (const float*)d_in[4];
    const float* fcw = (const float*)d_in[5];
    const float* fcb = (const float*)d_in[6];
    const int* v_idx = (const int*)d_in[7];
    const int* e_idx = (const int*)d_in[8];
    const int* link  = (const int*)d_in[9];
    float* out = (float*)d_out;

    const int NNZ = in_sizes[7];
    const int N   = in_sizes[0] / IN_DIM;
    const int L   = in_sizes[9] / 2;
    const int M   = MEDGES;
    const int Mpad = (int)align_up(M, 256);
    const int Npad = (int)align_up(N, 256);

    char* p = (char*)d_ws;
    auto carve = [&](size_t bytes) -> void* {
        void* r = (void*)p;
        p += align_up(bytes, 256);
        return r;
    };
    u16*  Xb     = (u16*)carve((size_t)N * IN_DIM * 2);   // X bf16; reused as h2b (N x 128)
    u16*  h1b    = (u16*)carve((size_t)N * H_DIM * 2);    // h1 bf16
    u16*  Aggb   = (u16*)carve((size_t)M * H_DIM * 2);    // Xe/He bf16 (GEMM A)
    u16*  Yb     = (u16*)carve((size_t)M * H_DIM * 2);    // Y1b / Y2b
    u16*  W1b    = (u16*)carve((size_t)IN_DIM * H_DIM * 2);
    u16*  W2b    = (u16*)carve((size_t)H_DIM * OUT_DIM * 2);
    int*  cntR_e = (int*)carve(((size_t)REP_E * Mpad + (size_t)REP_V * Npad) * 4);
    int*  cntR_v = cntR_e + (size_t)REP_E * Mpad;
    int*  e_lst  = (int*)carve((size_t)M * CAP_E * 4);
    int*  v_lst  = (int*)carve((size_t)N * CAP_V * 4);

    (void)hipMemsetAsync(cntR_e, 0, ((size_t)REP_E * Mpad + (size_t)REP_V * Npad) * 4, stream);

    const int tb = 256;

    // fused converts
    int nX  = N * IN_DIM / 4;
    int nW1 = IN_DIM * H_DIM / 4;
    int nW2 = H_DIM * OUT_DIM / 4;
    cvt_all<<<(nX + nW1 + nW2 + tb - 1) / tb, tb, 0, stream>>>(
        (const float4*)X, (ushort4*)Xb, nX,
        (const float4*)W1, (ushort4*)W1b, nW1,
        (const float4*)W2, (ushort4*)W2b, nW2);

    // one-pass replicated padded adjacency build
    build_lists<<<(NNZ + tb - 1) / tb, tb, 0, stream>>>(e_idx, v_idx, cntR_e, cntR_v,
                                                        e_lst, v_lst, Mpad, Npad, NNZ);

    // ---- conv1 ----
    seg_mean_w4<REP_E, SUB_E><<<((size_t)M * 64 + tb - 1) / tb, tb, 0, stream>>>(
        (const ushort4*)Xb, (ushort4*)Aggb, cntR_e, Mpad, e_lst, M, 0);
    gemm_mfma_bf16<<<dim3(H_DIM / 64, (M + 63) / 64), 256, 0, stream>>>(Aggb, W1b, b1, Yb, M, IN_DIM, H_DIM);
    seg_mean_w4<REP_V, SUB_V><<<((size_t)N * 64 + tb - 1) / tb, tb, 0, stream>>>(
        (const ushort4*)Yb, (ushort4*)h1b, cntR_v, Npad, v_lst, N, 1);

    // ---- conv2 ----
    seg_mean_w4<REP_E, SUB_E><<<((size_t)M * 64 + tb - 1) / tb, tb, 0, stream>>>(
        (const ushort4*)h1b, (ushort4*)Aggb, cntR_e, Mpad, e_lst, M, 0);
    gemm_mfma_bf16<<<dim3(OUT_DIM / 64, (M + 63) / 64), 256, 0, stream>>>(Aggb, W2b, b2, Yb, M, H_DIM, OUT_DIM);
    seg_mean_w2<REP_V, SUB_V><<<((size_t)N * 64 + tb - 1) / tb, tb, 0, stream>>>(
        (const ushort2*)Yb, (ushort2*)Xb, cntR_v, Npad, v_lst, N, 1);

    // ---- link head ----
    link_head<<<((size_t)L * 64 + tb - 1) / tb, tb, 0, stream>>>(
        (const ushort2*)Xb, link, fcw, fcb, out, L);
}

// Round 9
// 575.340 us; speedup vs baseline: 1.1914x; 1.1914x over previous
//
#include <hip/hip_runtime.h>
#include <cstdint>
#include <cstddef>

#define IN_DIM  256
#define H_DIM   256
#define OUT_DIM 128
#define MEDGES  20000

typedef unsigned short u16;
typedef unsigned int   u32;
typedef short bf16x8 __attribute__((ext_vector_type(8)));
typedef float f32x4  __attribute__((ext_vector_type(4)));

__device__ __forceinline__ float bf2f(u16 u) {
    u32 x = ((u32)u) << 16;
    float f;
    __builtin_memcpy(&f, &x, 4);
    return f;
}
// round-to-nearest-even float -> bf16 (finite inputs)
__device__ __forceinline__ u16 f2bf(float f) {
    u32 x;
    __builtin_memcpy(&x, &f, 4);
    u32 r = x + 0x7fffu + ((x >> 16) & 1u);
    return (u16)(r >> 16);
}

// ======================= fused convert fp32 -> bf16 (X, W1, W2) =======================
__global__ void cvt_all(const float4* __restrict__ X,  ushort4* __restrict__ Xb,  int nX,
                        const float4* __restrict__ W1, ushort4* __restrict__ W1b, int nW1,
                        const float4* __restrict__ W2, ushort4* __restrict__ W2b, int nW2)
{
    int i = blockIdx.x * blockDim.x + threadIdx.x;
    const float4* s; ushort4* d; int k;
    if (i < nX)                  { s = X;  d = Xb;  k = i; }
    else if (i < nX + nW1)       { s = W1; d = W1b; k = i - nX; }
    else if (i < nX + nW1 + nW2) { s = W2; d = W2b; k = i - nX - nW1; }
    else return;
    float4 v = s[k];
    ushort4 o;
    o.x = f2bf(v.x); o.y = f2bf(v.y); o.z = f2bf(v.z); o.w = f2bf(v.w);
    d[k] = o;
}

// ======================= CSR build =======================
// Split-side: 2*nnz threads, each does ONE atomic + ONE rank write (halves the
// per-thread dependent chain vs one thread doing both sides).
__global__ void hist_rank_split(const int* __restrict__ e_idx, const int* __restrict__ v_idx,
                                int* __restrict__ cnt_e, int* __restrict__ cnt_v,
                                int* __restrict__ rank_e, int* __restrict__ rank_v, int nnz)
{
    int i = blockIdx.x * blockDim.x + threadIdx.x;
    if (i < nnz) {
        rank_e[i] = atomicAdd(&cnt_e[e_idx[i]], 1);
    } else if (i < 2 * nnz) {
        int j = i - nnz;
        rank_v[j] = atomicAdd(&cnt_v[v_idx[j]], 1);
    }
}

#define SCAN_B 1024
// Combined E+V block scan: blocks [0,nbE) handle cnt_e->e_off, [nbE,nbE+nbV) handle cnt_v->v_off.
__global__ void scan_block_both(const int* __restrict__ cnt_e, int* __restrict__ e_off,
                                const int* __restrict__ cnt_v, int* __restrict__ v_off,
                                int* __restrict__ bsums, int m, int n, int nbE)
{
    __shared__ int s[SCAN_B];
    const int* in; int* out; int* bs; int nn; int blk;
    if ((int)blockIdx.x < nbE) { in = cnt_e; out = e_off; bs = bsums;      nn = m; blk = blockIdx.x; }
    else                       { in = cnt_v; out = v_off; bs = bsums + 64; nn = n; blk = blockIdx.x - nbE; }
    int gid = blk * SCAN_B + threadIdx.x;
    int x = (gid < nn) ? in[gid] : 0;
    s[threadIdx.x] = x;
    __syncthreads();
    for (int off = 1; off < SCAN_B; off <<= 1) {
        int v = (threadIdx.x >= off) ? s[threadIdx.x - off] : 0;
        __syncthreads();
        s[threadIdx.x] += v;
        __syncthreads();
    }
    if (gid < nn) out[gid] = s[threadIdx.x] - x;   // exclusive
    if (threadIdx.x == SCAN_B - 1) bs[blk] = s[SCAN_B - 1];
}

// One block; lane 0 scans E bsums (+tail), lane 1 scans V bsums (+tail).
__global__ void scan_top_both(int* __restrict__ bsums, int nbE, int nbV,
                              int* __restrict__ e_off, int* __restrict__ v_off,
                              int m, int n, int nnz)
{
    int t = threadIdx.x;
    if (t == 0) {
        int run = 0;
        for (int i = 0; i < nbE; ++i) { int v = bsums[i]; bsums[i] = run; run += v; }
        e_off[m] = nnz;
    } else if (t == 1) {
        int run = 0;
        for (int i = 0; i < nbV; ++i) { int v = bsums[64 + i]; bsums[64 + i] = run; run += v; }
        v_off[n] = nnz;
    }
}

__global__ void scan_add_both(int* __restrict__ e_off, int* __restrict__ v_off,
                              const int* __restrict__ bsums, int m, int n, int nbE)
{
    int* out; const int* bs; int nn; int blk;
    if ((int)blockIdx.x < nbE) { out = e_off; bs = bsums;      nn = m; blk = blockIdx.x; }
    else                       { out = v_off; bs = bsums + 64; nn = n; blk = blockIdx.x - nbE; }
    int gid = blk * SCAN_B + threadIdx.x;
    if (gid < nn) out[gid] += bs[blk];
}

// Split-side scatter: 2*nnz threads, each one random store.
__global__ void scatter_split(const int* __restrict__ e_idx, const int* __restrict__ v_idx,
                              const int* __restrict__ e_off, const int* __restrict__ v_off,
                              const int* __restrict__ rank_e, const int* __restrict__ rank_v,
                              int* __restrict__ e_list, int* __restrict__ v_list, int nnz)
{
    int i = blockIdx.x * blockDim.x + threadIdx.x;
    if (i < nnz) {
        int e = e_idx[i];
        e_list[e_off[e] + rank_e[i]] = v_idx[i];
    } else if (i < 2 * nnz) {
        int j = i - nnz;
        int v = v_idx[j];
        v_list[v_off[v] + rank_v[j]] = e_idx[j];
    }
}

// ======================= segment mean: wave-per-segment =======================
// D = 256: 64 lanes x ushort4 (8 B/lane). Unroll-4 rows for MLP; bounds scalarized.
__global__ void seg_mean_w4(const ushort4* __restrict__ src, ushort4* __restrict__ dst,
                            const int* __restrict__ off, const int* __restrict__ lst,
                            int nseg, int do_relu)
{
    int wid  = (blockIdx.x * blockDim.x + threadIdx.x) >> 6;
    int lane = threadIdx.x & 63;
    if (wid >= nseg) return;
    int beg = __builtin_amdgcn_readfirstlane(off[wid]);
    int end = __builtin_amdgcn_readfirstlane(off[wid + 1]);
    float ax = 0.f, ay = 0.f, az = 0.f, aw = 0.f;
    int j = beg;
    for (; j + 3 < end; j += 4) {
        int i0 = lst[j], i1 = lst[j + 1], i2 = lst[j + 2], i3 = lst[j + 3];
        ushort4 a = src[(size_t)i0 * 64 + lane];
        ushort4 b = src[(size_t)i1 * 64 + lane];
        ushort4 c = src[(size_t)i2 * 64 + lane];
        ushort4 d = src[(size_t)i3 * 64 + lane];
        ax += bf2f(a.x) + bf2f(b.x) + bf2f(c.x) + bf2f(d.x);
        ay += bf2f(a.y) + bf2f(b.y) + bf2f(c.y) + bf2f(d.y);
        az += bf2f(a.z) + bf2f(b.z) + bf2f(c.z) + bf2f(d.z);
        aw += bf2f(a.w) + bf2f(b.w) + bf2f(c.w) + bf2f(d.w);
    }
    for (; j < end; ++j) {
        ushort4 a = src[(size_t)lst[j] * 64 + lane];
        ax += bf2f(a.x); ay += bf2f(a.y); az += bf2f(a.z); aw += bf2f(a.w);
    }
    int cnt = end - beg;
    float inv = (cnt > 0) ? 1.f / (float)cnt : 0.f;
    ax *= inv; ay *= inv; az *= inv; aw *= inv;
    if (do_relu) {
        ax = fmaxf(ax, 0.f); ay = fmaxf(ay, 0.f);
        az = fmaxf(az, 0.f); aw = fmaxf(aw, 0.f);
    }
    ushort4 o;
    o.x = f2bf(ax); o.y = f2bf(ay); o.z = f2bf(az); o.w = f2bf(aw);
    dst[(size_t)wid * 64 + lane] = o;
}

// D = 128: ushort2 per lane.
__global__ void seg_mean_w2(const ushort2* __restrict__ src, ushort2* __restrict__ dst,
                            const int* __restrict__ off, const int* __restrict__ lst,
                            int nseg, int do_relu)
{
    int wid  = (blockIdx.x * blockDim.x + threadIdx.x) >> 6;
    int lane = threadIdx.x & 63;
    if (wid >= nseg) return;
    int beg = __builtin_amdgcn_readfirstlane(off[wid]);
    int end = __builtin_amdgcn_readfirstlane(off[wid + 1]);
    float ax = 0.f, ay = 0.f;
    int j = beg;
    for (; j + 3 < end; j += 4) {
        int i0 = lst[j], i1 = lst[j + 1], i2 = lst[j + 2], i3 = lst[j + 3];
        ushort2 a = src[(size_t)i0 * 64 + lane];
        ushort2 b = src[(size_t)i1 * 64 + lane];
        ushort2 c = src[(size_t)i2 * 64 + lane];
        ushort2 d = src[(size_t)i3 * 64 + lane];
        ax += bf2f(a.x) + bf2f(b.x) + bf2f(c.x) + bf2f(d.x);
        ay += bf2f(a.y) + bf2f(b.y) + bf2f(c.y) + bf2f(d.y);
    }
    for (; j < end; ++j) {
        ushort2 a = src[(size_t)lst[j] * 64 + lane];
        ax += bf2f(a.x); ay += bf2f(a.y);
    }
    int cnt = end - beg;
    float inv = (cnt > 0) ? 1.f / (float)cnt : 0.f;
    ax *= inv; ay *= inv;
    if (do_relu) { ax = fmaxf(ax, 0.f); ay = fmaxf(ay, 0.f); }
    ushort2 o;
    o.x = f2bf(ax); o.y = f2bf(ay);
    dst[(size_t)wid * 64 + lane] = o;
}

// ======================= MFMA bf16 GEMM + bias, bf16 out =======================
#define GSTRIDE 40   // LDS row stride in elements (80 B)
__global__ __launch_bounds__(256) void gemm_mfma_bf16(const u16* __restrict__ A,
                                                      const u16* __restrict__ W,
                                                      const float* __restrict__ bias,
                                                      u16* __restrict__ C,
                                                      int R, int K, int Cc)
{
    __shared__ __align__(16) u16 As[64 * GSTRIDE];   // [row][k] 64x32
    __shared__ __align__(16) u16 Bs[64 * GSTRIDE];   // [n][k]   64x32 (transposed)

    int tid  = threadIdx.x;
    int wave = tid >> 6;
    int lane = tid & 63;
    int quad = lane >> 4;
    int l16  = lane & 15;

    int row0 = blockIdx.y * 64;
    int col0 = blockIdx.x * 64;

    f32x4 acc[4] = {};

    int ar   = tid >> 2;   // 0..63 A row
    int aseg = tid & 3;    // k-offset 8*aseg
    int bk   = tid >> 3;   // 0..31 W k-row
    int bn   = tid & 7;    // n-offset 8*bn

    for (int k0 = 0; k0 < K; k0 += 32) {
        bf16x8 av = {};
        int gr = row0 + ar;
        if (gr < R) av = *(const bf16x8*)&A[(size_t)gr * K + k0 + 8 * aseg];
        *(bf16x8*)&As[ar * GSTRIDE + 8 * aseg] = av;
        bf16x8 wv = *(const bf16x8*)&W[(size_t)(k0 + bk) * Cc + col0 + 8 * bn];
#pragma unroll
        for (int j = 0; j < 8; ++j)
            Bs[(8 * bn + j) * GSTRIDE + bk] = ((const u16*)&wv)[j];
        __syncthreads();

        bf16x8 af = *(const bf16x8*)&As[(16 * wave + l16) * GSTRIDE + 8 * quad];
#pragma unroll
        for (int nt = 0; nt < 4; ++nt) {
            bf16x8 bfv = *(const bf16x8*)&Bs[(16 * nt + l16) * GSTRIDE + 8 * quad];
            acc[nt] = __builtin_amdgcn_mfma_f32_16x16x32_bf16(af, bfv, acc[nt], 0, 0, 0);
        }
        __syncthreads();
    }

#pragma unroll
    for (int nt = 0; nt < 4; ++nt) {
        int col = col0 + 16 * nt + l16;
        float bv = bias[col];
#pragma unroll
        for (int r = 0; r < 4; ++r) {
            int grow = row0 + 16 * wave + 4 * quad + r;
            if (grow < R) C[(size_t)grow * Cc + col] = f2bf(acc[nt][r] + bv);
        }
    }
}

// ======================= link head =======================
__global__ void link_head(const ushort2* __restrict__ h2, const int* __restrict__ link,
                          const float* __restrict__ fc_w, const float* __restrict__ fc_b,
                          float* __restrict__ out, int L)
{
    int gtid = blockIdx.x * blockDim.x + threadIdx.x;
    int wid  = gtid >> 6;
    int lane = threadIdx.x & 63;
    if (wid >= L) return;
    const int Dh = OUT_DIM / 2;   // 64 pairs
    int a = link[2 * wid + 0];
    int b = link[2 * wid + 1];
    ushort2 ra = h2[(size_t)a * Dh + lane];
    ushort2 rb = h2[(size_t)b * Dh + lane];
    float2 w = *(const float2*)&fc_w[2 * lane];
    float acc = 0.5f * ((bf2f(ra.x) + bf2f(rb.x)) * w.x + (bf2f(ra.y) + bf2f(rb.y)) * w.y);
#pragma unroll
    for (int off = 32; off; off >>= 1) acc += __shfl_xor(acc, off, 64);
    if (lane == 0) out[wid] = 1.f / (1.f + expf(-(acc + fc_b[0])));
}

// ======================= launch =======================

static inline size_t align_up(size_t x, size_t a) { return (x + a - 1) & ~(a - 1); }

extern "C" void kernel_launch(void* const* d_in, const int* in_sizes, int n_in,
                              void* d_out, int out_size, void* d_ws, size_t ws_size,
                              hipStream_t stream)
{
    const float* X   = (const float*)d_in[0];
    const float* W1  = (const float*)d_in[1];
    const float* b1  = (const float*)d_in[2];
    const float* W2  = (const float*)d_in[3];
    const float* b2  = (const float*)d_in[4];
    const float* fcw = (const float*)d_in[5];
    const float* fcb = (const float*)d_in[6];
    const int* v_idx = (const int*)d_in[7];
    const int* e_idx = (const int*)d_in[8];
    const int* link  = (const int*)d_in[9];
    float* out = (float*)d_out;

    const int NNZ = in_sizes[7];
    const int N   = in_sizes[0] / IN_DIM;
    const int L   = in_sizes[9] / 2;
    const int M   = MEDGES;
    const int Mpad = (int)align_up(M, 64);

    char* p = (char*)d_ws;
    auto carve = [&](size_t bytes) -> void* {
        void* r = (void*)p;
        p += align_up(bytes, 256);
        return r;
    };
    u16*  Xb    = (u16*)carve((size_t)N * IN_DIM * 2);   // X bf16; reused as h2b (N x 128)
    u16*  h1b   = (u16*)carve((size_t)N * H_DIM * 2);    // h1 bf16
    u16*  Aggb  = (u16*)carve((size_t)M * H_DIM * 2);    // Xe/He bf16 (GEMM A)
    u16*  Yb    = (u16*)carve((size_t)M * H_DIM * 2);    // Y1b / Y2b
    u16*  W1b   = (u16*)carve((size_t)IN_DIM * H_DIM * 2);
    u16*  W2b   = (u16*)carve((size_t)H_DIM * OUT_DIM * 2);
    int*  e_off = (int*)carve((size_t)(M + 1) * 4);
    int*  v_off = (int*)carve((size_t)(N + 1) * 4);
    int*  cnt_e = (int*)carve((size_t)(Mpad + N) * 4);   // cnt_e ++ cnt_v, one memset
    int*  cnt_v = cnt_e + Mpad;
    int*  rank_e= (int*)carve((size_t)NNZ * 4);
    int*  rank_v= (int*)carve((size_t)NNZ * 4);
    int*  e_lst = (int*)carve((size_t)NNZ * 4);
    int*  v_lst = (int*)carve((size_t)NNZ * 4);
    int*  bsums = (int*)carve(1024);                     // [0,64) E, [64,64+nbV) V

    (void)hipMemsetAsync(cnt_e, 0, (size_t)(Mpad + N) * 4, stream);

    const int tb = 256;

    // fused converts (overlap with CSR build on other CUs)
    int nX  = N * IN_DIM / 4;
    int nW1 = IN_DIM * H_DIM / 4;
    int nW2 = H_DIM * OUT_DIM / 4;
    cvt_all<<<(nX + nW1 + nW2 + tb - 1) / tb, tb, 0, stream>>>(
        (const float4*)X, (ushort4*)Xb, nX,
        (const float4*)W1, (ushort4*)W1b, nW1,
        (const float4*)W2, (ushort4*)W2b, nW2);

    // split-side hist: 2*NNZ threads, one atomic each
    hist_rank_split<<<(2 * NNZ + tb - 1) / tb, tb, 0, stream>>>(e_idx, v_idx, cnt_e, cnt_v,
                                                                rank_e, rank_v, NNZ);

    // combined parallel scans (E blocks ++ V blocks in one launch)
    int nbE = (M + SCAN_B - 1) / SCAN_B;
    int nbV = (N + SCAN_B - 1) / SCAN_B;
    scan_block_both<<<nbE + nbV, SCAN_B, 0, stream>>>(cnt_e, e_off, cnt_v, v_off, bsums, M, N, nbE);
    scan_top_both<<<1, 64, 0, stream>>>(bsums, nbE, nbV, e_off, v_off, M, N, NNZ);
    scan_add_both<<<nbE + nbV, SCAN_B, 0, stream>>>(e_off, v_off, bsums, M, N, nbE);

    // split-side scatter: 2*NNZ threads, one random store each
    scatter_split<<<(2 * NNZ + tb - 1) / tb, tb, 0, stream>>>(e_idx, v_idx, e_off, v_off,
                                                              rank_e, rank_v, e_lst, v_lst, NNZ);

    // ---- conv1 ----
    seg_mean_w4<<<((size_t)M * 64 + tb - 1) / tb, tb, 0, stream>>>(
        (const ushort4*)Xb, (ushort4*)Aggb, e_off, e_lst, M, 0);
    gemm_mfma_bf16<<<dim3(H_DIM / 64, (M + 63) / 64), 256, 0, stream>>>(Aggb, W1b, b1, Yb, M, IN_DIM, H_DIM);
    seg_mean_w4<<<((size_t)N * 64 + tb - 1) / tb, tb, 0, stream>>>(
        (const ushort4*)Yb, (ushort4*)h1b, v_off, v_lst, N, 1);

    // ---- conv2 ----
    seg_mean_w4<<<((size_t)M * 64 + tb - 1) / tb, tb, 0, stream>>>(
        (const ushort4*)h1b, (ushort4*)Aggb, e_off, e_lst, M, 0);
    gemm_mfma_bf16<<<dim3(OUT_DIM / 64, (M + 63) / 64), 256, 0, stream>>>(Aggb, W2b, b2, Yb, M, H_DIM, OUT_DIM);
    seg_mean_w2<<<((size_t)N * 64 + tb - 1) / tb, tb, 0, stream>>>(
        (const ushort2*)Yb, (ushort2*)Xb, v_off, v_lst, N, 1);

    // ---- link head ----
    link_head<<<((size_t)L * 64 + tb - 1) / tb, tb, 0, stream>>>(
        (const ushort2*)Xb, link, fcw, fcb, out, L);
}